// Round 9
// baseline (417.469 us; speedup 1.0000x reference)
//
#include <hip/hip_runtime.h>

// Problem constants
#define E_ 158
#define F_ 2049
#define T_ 64
#define C_ 2
#define B_ 8
#define EF 323742           // E_*F_
#define EF2 161871          // EF/2 (float2 units per t-row)
#define EFT 20719488        // EF*T_ (per-batch element count)
#define NOUT 165755904      // B_*EFT
#define N4TOT 41438976      // NOUT/4 (float4s total); 161871 blocks x 256 exact

// rx segmentation: 120 segments over EF2 float2s
#define NSEG 120
#define SEGF2 1349          // ceil(161871/120); last = 161871-119*1349 = 1340
#define LASTF2 1340

typedef float vfloat4 __attribute__((ext_vector_type(4)));  // native clang vec

// ---------------------------------------------------------------------------
// Kernel 1: proj[b,k] = xind[b,0]*W[k,0] + xind[b,1]*W[k,1] + bias[k]
// Written directly into the anchor region of d_out (anchor == proj flat).
// ---------------------------------------------------------------------------
__global__ __launch_bounds__(256) void proj_kernel(
    const float* __restrict__ xind, const float* __restrict__ W,
    const float* __restrict__ bias, float* __restrict__ anchor)
{
    unsigned int idx = blockIdx.x * 256u + threadIdx.x;
    if (idx >= (unsigned int)(B_ * EF)) return;
    unsigned int b = idx / (unsigned int)EF;
    unsigned int k = idx - b * (unsigned int)EF;
    anchor[idx] = xind[b * 2 + 0] * W[2 * k + 0]
                + xind[b * 2 + 1] * W[2 * k + 1]
                + bias[k];
}

// ---------------------------------------------------------------------------
// Kernel 2: partial dots with proj staged in LDS ONCE per block.
// Block (s = blockIdx.x, b = blockIdx.y): stages proj[b, seg_s] (<=10.8KB)
// into LDS, then each of the 4 waves computes 16 t-dots: wave w, step j ->
// t = w*16+j, 64-lane dot of xs[b, t*EF + seg_s] against LDS proj, shfl
// reduce, lane 0 writes part[(b*64+t)*NSEG + s]. proj HBM traffic: 10 MB
// total (was up to 663 MB of re-read requests in round 7's layout).
// ---------------------------------------------------------------------------
__global__ __launch_bounds__(256) void rx_all_kernel(
    const float* __restrict__ xs, const float* __restrict__ proj,
    float* __restrict__ part)
{
    const int s = blockIdx.x;             // [0, NSEG)
    const int b = blockIdx.y;             // [0, B_)
    const int len = (s == NSEG - 1) ? LASTF2 : SEGF2;

    __shared__ float2 sproj[SEGF2];
    {
        const float2* __restrict__ pp =
            (const float2*)proj + (size_t)b * EF2 + (size_t)s * SEGF2;
        for (int i = threadIdx.x; i < len; i += 256)
            sproj[i] = pp[i];
    }
    __syncthreads();

    const int w = threadIdx.x >> 6;       // wave 0..3
    const int lane = threadIdx.x & 63;
    const float2* __restrict__ xb =
        (const float2*)xs + (size_t)b * (EFT / 2) + (size_t)s * SEGF2;

    #pragma unroll 2
    for (int j = 0; j < 16; ++j) {
        const int t = w * 16 + j;
        const float2* __restrict__ xp = xb + (size_t)t * EF2;
        float acc = 0.f;
        for (int i = lane; i < len; i += 64) {
            float2 x = xp[i];
            float2 p = sproj[i];
            acc += x.x * p.x + x.y * p.y;
        }
        #pragma unroll
        for (int off = 32; off > 0; off >>= 1)
            acc += __shfl_down(acc, off, 64);
        if (lane == 0)
            part[(size_t)(b * 64 + t) * NSEG + s] = acc;
    }
}

// ---------------------------------------------------------------------------
// Kernel 3: Rx[bt] = sum_s part[bt*NSEG+s], one block, fixed order ->
// bitwise deterministic across replays.
// ---------------------------------------------------------------------------
__global__ __launch_bounds__(512) void rx_final_kernel(
    const float* __restrict__ part, float* __restrict__ Rx)
{
    const int bt = threadIdx.x;           // b*64 + t
    float r = 0.f;
    for (int s = 0; s < NSEG; ++s) r += part[bt * NSEG + s];
    Rx[bt] = r;
}

// ---------------------------------------------------------------------------
// Kernel 4: out[i = b*EFT + k*T + t] = xs[i] * proj[b,k] * Rx[b,t].
// Nontemporal on the two 663MB streams (no reuse exists for either).
// Reverse block order retained (harmless; helps if any L3 lingering).
// ---------------------------------------------------------------------------
__global__ __launch_bounds__(256) void gate_all_kernel(
    const float* __restrict__ xs, const float* __restrict__ proj,
    const float* __restrict__ Rx, float* __restrict__ out)
{
    unsigned int rb = (unsigned int)(gridDim.x - 1u - blockIdx.x);
    unsigned int idx4 = rb * 256u + threadIdx.x;   // [0, N4TOT), exact cover
    unsigned int i = idx4 * 4u;
    unsigned int b = i / (unsigned int)EFT;
    unsigned int r = i - b * (unsigned int)EFT;
    unsigned int k = r >> 6;
    unsigned int t = r & 63u;                      // t % 4 == 0

    float p = proj[(size_t)b * EF + k];
    const float4 rx4 = *(const float4*)(Rx + b * T_ + t);
    vfloat4 x = __builtin_nontemporal_load(&((const vfloat4*)xs)[idx4]);
    vfloat4 o;
    o.x = x.x * p * rx4.x;
    o.y = x.y * p * rx4.y;
    o.z = x.z * p * rx4.z;
    o.w = x.w * p * rx4.w;
    __builtin_nontemporal_store(o, &((vfloat4*)out)[idx4]);
}

extern "C" void kernel_launch(void* const* d_in, const int* in_sizes, int n_in,
                              void* d_out, int out_size, void* d_ws, size_t ws_size,
                              hipStream_t stream)
{
    const float* xs   = (const float*)d_in[0];   // [B,E,F,T]
    const float* xind = (const float*)d_in[1];   // [B,C]
    const float* W    = (const float*)d_in[2];   // [E*F, C]
    const float* bias = (const float*)d_in[3];   // [E*F]

    float* out    = (float*)d_out;                    // [B,E,F,T] flat
    float* anchor = (float*)d_out + (size_t)NOUT;     // [B,F,E] flat == proj
    float* part   = (float*)d_ws;                     // [512][NSEG] = 61440 f
    float* Rx     = (float*)d_ws + 512 * NSEG;        // [512] f (16B-aligned)

    // 1) proj -> anchor region (doubles as proj operand)
    {
        const int n = B_ * EF;                        // 2,589,936
        proj_kernel<<<(n + 255) / 256, 256, 0, stream>>>(xind, W, bias, anchor);
    }
    // 2) partial dots: 960 blocks, proj staged in LDS once per block
    rx_all_kernel<<<dim3(NSEG, B_), 256, 0, stream>>>(xs, anchor, part);
    // 3) finalize Rx (deterministic fixed-order sum)
    rx_final_kernel<<<1, 512, 0, stream>>>(part, Rx);
    // 4) gate, nontemporal streams
    gate_all_kernel<<<N4TOT / 256, 256, 0, stream>>>(xs, anchor, Rx, out);
}

// Round 10
// 374.313 us; speedup vs baseline: 1.1153x; 1.1153x over previous
//
#include <hip/hip_runtime.h>

// Problem constants
#define E_ 158
#define F_ 2049
#define T_ 64
#define C_ 2
#define B_ 8
#define EF 323742           // E_*F_
#define EF2 161871          // EF/2 (float2 units per t-chunk)
#define EFT 20719488        // EF*T_ (per-batch element count)
#define NOUT 165755904      // B_*EFT
#define N4B 5179872         // EFT/4 (float4s per batch)
#define NSEG 16
#define SEG2 10117          // ceil(EF2/NSEG); last segment = 10116

// gate config: per-batch grid-stride
#define GBLK 512            // blocks per batch (x-dim); 512*256 = 131072 threads
#define GSTRIDE (GBLK * 256)   // divisible by 16 -> t invariant per thread

typedef float vfloat4 __attribute__((ext_vector_type(4)));  // nt-builtin-compatible

// ---------------------------------------------------------------------------
// Kernel 1: proj[b,k] = xind[b,0]*W[k,0] + xind[b,1]*W[k,1] + bias[k]
// Written directly into the anchor region of d_out (anchor == proj flat).
// ---------------------------------------------------------------------------
__global__ __launch_bounds__(256) void proj_kernel(
    const float* __restrict__ xind, const float* __restrict__ W,
    const float* __restrict__ bias, float* __restrict__ anchor)
{
    unsigned int idx = blockIdx.x * 256u + threadIdx.x;
    if (idx >= (unsigned int)(B_ * EF)) return;
    unsigned int b = idx / (unsigned int)EF;
    unsigned int k = idx - b * (unsigned int)EF;
    anchor[idx] = xind[b * 2 + 0] * W[2 * k + 0]
                + xind[b * 2 + 1] * W[2 * k + 1]
                + bias[k];
}

// ---------------------------------------------------------------------------
// Kernel 2 (round-7 proven form): partial dots. Block (b,t,s) sums an 81KB
// contiguous chunk of xs_flat[b, t*EF + seg_s] against proj[b, seg_s].
// 8192 blocks saturate HBM; same-(b,s) blocks are 16 apart -> same XCD ->
// proj segment re-reads are L2-resident.
// ---------------------------------------------------------------------------
__global__ __launch_bounds__(256) void rx_all_kernel(
    const float* __restrict__ xs, const float* __restrict__ proj,
    float* __restrict__ part)
{
    const int blk = blockIdx.x;           // b*1024 + t*16 + s
    const int b = blk >> 10;
    const int t = (blk >> 4) & 63;
    const int s = blk & 15;
    const int len2 = (s == NSEG - 1) ? (EF2 - (NSEG - 1) * SEG2) : SEG2;

    const float2* __restrict__ xp =
        (const float2*)(xs + (size_t)b * EFT) + (size_t)t * EF2 + (size_t)s * SEG2;
    const float2* __restrict__ pp =
        (const float2*)(proj + (size_t)b * EF) + (size_t)s * SEG2;

    float acc = 0.f;
    #pragma unroll 4
    for (int i = threadIdx.x; i < len2; i += 256) {
        float2 x = xp[i];
        float2 p = pp[i];
        acc += x.x * p.x + x.y * p.y;
    }
    #pragma unroll
    for (int off = 32; off > 0; off >>= 1)
        acc += __shfl_down(acc, off, 64);

    __shared__ float sacc[4];
    if ((threadIdx.x & 63) == 0) sacc[threadIdx.x >> 6] = acc;
    __syncthreads();
    if (threadIdx.x == 0)
        part[blk] = sacc[0] + sacc[1] + sacc[2] + sacc[3];
}

// ---------------------------------------------------------------------------
// Kernel 3: Rx[bt] = sum_s part[bt*16+s], one block, fixed order -> bitwise
// deterministic across replays.
// ---------------------------------------------------------------------------
__global__ __launch_bounds__(512) void rx_final_kernel(
    const float* __restrict__ part, float* __restrict__ Rx)
{
    const int bt = threadIdx.x;           // b*64 + t
    float r = 0.f;
    #pragma unroll
    for (int s = 0; s < NSEG; ++s) r += part[bt * NSEG + s];
    Rx[bt] = r;
}

// ---------------------------------------------------------------------------
// Kernel 4: gate, per-batch 2D grid-stride. b = blockIdx.y (no division);
// stride divisible by 16 -> each thread's t (and rx4) is loop-invariant.
// ~40 float4 per thread amortizes block setup (was 1 float4/thread over
// 161871 blocks). Nontemporal on both 663MB streams (zero reuse).
// ---------------------------------------------------------------------------
__global__ __launch_bounds__(256) void gate_all_kernel(
    const float* __restrict__ xs, const float* __restrict__ proj,
    const float* __restrict__ Rx, float* __restrict__ out)
{
    const int b = blockIdx.y;
    const unsigned base = blockIdx.x * 256u + threadIdx.x;   // [0, GSTRIDE)

    // t0 = (idx4 & 15)*4 is invariant across the stride loop
    const float4 rx4 = *(const float4*)(Rx + b * T_ + (base & 15u) * 4u);
    const float* __restrict__ pj = proj + (size_t)b * EF;
    const vfloat4* __restrict__ xs4 = (const vfloat4*)xs + (size_t)b * N4B;
    vfloat4* __restrict__ out4 = (vfloat4*)out + (size_t)b * N4B;

    #pragma unroll 2
    for (unsigned idx4 = base; idx4 < (unsigned)N4B; idx4 += GSTRIDE) {
        float p = pj[idx4 >> 4];                 // k = idx4/16, L2-resident
        vfloat4 x = __builtin_nontemporal_load(&xs4[idx4]);
        vfloat4 o;
        o.x = x.x * p * rx4.x;
        o.y = x.y * p * rx4.y;
        o.z = x.z * p * rx4.z;
        o.w = x.w * p * rx4.w;
        __builtin_nontemporal_store(o, &out4[idx4]);
    }
}

extern "C" void kernel_launch(void* const* d_in, const int* in_sizes, int n_in,
                              void* d_out, int out_size, void* d_ws, size_t ws_size,
                              hipStream_t stream)
{
    const float* xs   = (const float*)d_in[0];   // [B,E,F,T]
    const float* xind = (const float*)d_in[1];   // [B,C]
    const float* W    = (const float*)d_in[2];   // [E*F, C]
    const float* bias = (const float*)d_in[3];   // [E*F]

    float* out    = (float*)d_out;                    // [B,E,F,T] flat
    float* anchor = (float*)d_out + (size_t)NOUT;     // [B,F,E] flat == proj
    float* part   = (float*)d_ws;                     // [B][64][16] = 8192 f
    float* Rx     = (float*)d_ws + B_ * T_ * NSEG;    // [B][64] f (16B-aligned)

    // 1) proj -> anchor region (doubles as proj operand)
    {
        const int n = B_ * EF;                        // 2,589,936
        proj_kernel<<<(n + 255) / 256, 256, 0, stream>>>(xind, W, bias, anchor);
    }
    // 2) partial dots: 8192 contiguous-chunk blocks (round-7 proven)
    rx_all_kernel<<<B_ * T_ * NSEG, 256, 0, stream>>>(xs, anchor, part);
    // 3) finalize Rx (deterministic fixed-order sum)
    rx_final_kernel<<<1, 512, 0, stream>>>(part, Rx);
    // 4) gate: per-batch grid-stride, nt streams
    gate_all_kernel<<<dim3(GBLK, B_), 256, 0, stream>>>(xs, anchor, Rx, out);
}